// Round 6
// baseline (361.290 us; speedup 1.0000x reference)
//
#include <hip/hip_runtime.h>

// ---------------------------------------------------------------------------
// SAM vision attention (B=1, H=W=64, C=768, 12 heads x hd=64). fp32 I/O.
// cvt -> QKV proj (128-tile) -> rel_w -> flash attn (S^T form) -> out proj
// MFMA v_mfma_f32_16x16x32_bf16 layouts (guide-verified m89/m91):
//   A/B frag: [m|n = lane&15][k = (lane>>4)*8 + j]   (8 bf16 / lane, b128)
//   C/D     : col = lane&15, row = (lane>>4)*4 + reg (4 f32 / lane)
// R6: attn computes S^T = K*Q^T with KEYS split across waves (16/wave):
//  - Q^T B-frags in registers (loop-invariant) -> K frag reads 2 b128/tile
//  - S^T C-layout == P^T B-frag layout over a 2-tile pair (K=32), with V
//    tokens stored interleaved sc = w*32+quad*8+tile*4+reg  -> P NEVER
//    touches LDS (exp -> v_perm pack -> MFMA in registers)
//  - PV: O^T = V*P^T, V frag reads 2 b128/tile; O^T 64 f32/lane partials,
//    cross-wave reduced via LDS atomicAdd in epilogue
//  - K/V staged with XOR-ish address swizzle so the new frag reads stay ~2-way
//  - rel_h via prologue MFMA -> LDS scalar broadcast reads (4/tile)
// LDS per tile-wave: ~4 b128 + 4 b16 (was 18 b128 + 8 b32) => ~4x less traffic
// ---------------------------------------------------------------------------

typedef __attribute__((ext_vector_type(8))) short bf16x8;
typedef __attribute__((ext_vector_type(4))) float f32x4;
typedef __attribute__((ext_vector_type(4))) short s16x4;
typedef __attribute__((ext_vector_type(2))) unsigned int u32x2;
typedef __attribute__((ext_vector_type(4))) unsigned int u32x4;

__device__ __forceinline__ float b2f(unsigned short h) {
    union { unsigned int u; float f; } v; v.u = ((unsigned int)h) << 16; return v.f;
}
__device__ __forceinline__ unsigned short f2b(float f) {
    union { float f; unsigned int u; } v; v.f = f;
    unsigned int r = v.u + 0x7FFFu + ((v.u >> 16) & 1u);  // RNE
    return (unsigned short)(r >> 16);
}
__device__ __forceinline__ float lo16f(unsigned int u) {
    union { unsigned int u; float f; } v; v.u = u << 16; return v.f;
}
__device__ __forceinline__ float hi16f(unsigned int u) {
    union { unsigned int u; float f; } v; v.u = u & 0xffff0000u; return v.f;
}
__device__ __forceinline__ unsigned int fbits(float f) {
    union { float f; unsigned int u; } v; v.f = f; return v.u;
}
__device__ __forceinline__ void gl_lds16(const void* g, void* l) {
    __builtin_amdgcn_global_load_lds(
        (const __attribute__((address_space(1))) void*)g,
        (__attribute__((address_space(3))) void*)l, 16, 0, 0);
}

// ---------------------------------------------------------------------------
// fp32 -> bf16 bulk convert into one contiguous region (quad-indexed).
// ---------------------------------------------------------------------------
__global__ __launch_bounds__(256) void cvt_bf16(
        const float* __restrict__ hs, const float* __restrict__ wq,
        const float* __restrict__ wk, const float* __restrict__ wv,
        const float* __restrict__ wo, const float* __restrict__ rph,
        const float* __restrict__ rpw, unsigned short* __restrict__ dst) {
    const int idx = blockIdx.x * 256 + threadIdx.x;
    if (idx >= 1380320) return;
    const float* src;
    int off;
    if      (idx < 786432)  { src = hs;  off = idx; }
    else if (idx < 933888)  { src = wq;  off = idx - 786432; }
    else if (idx < 1081344) { src = wk;  off = idx - 933888; }
    else if (idx < 1228800) { src = wv;  off = idx - 1081344; }
    else if (idx < 1376256) { src = wo;  off = idx - 1228800; }
    else if (idx < 1378288) { src = rph; off = idx - 1376256; }
    else                    { src = rpw; off = idx - 1378288; }
    const float4 v = ((const float4*)src)[off];
    s16x4 o;
    o[0] = (short)f2b(v.x); o[1] = (short)f2b(v.y);
    o[2] = (short)f2b(v.z); o[3] = (short)f2b(v.w);
    *(s16x4*)(dst + (size_t)idx * 4) = o;
}

// ---------------------------------------------------------------------------
// Fused QKV projection, 128x128 tile. M=4096, N=768 per z, K=768, BK=32.
// z: 0->q [n>>6][m][n&63], 1->k same, 2->v^T with PAIR-interleaved tokens:
// within a 128-token pair group, token (tile*64 + kk), kk = i*16+quad*4+reg,
// stored at col = i*32 + quad*8 + tile*4 + reg.
// ---------------------------------------------------------------------------
__launch_bounds__(256, 3)
__global__ void qkv128(const unsigned short* __restrict__ X,
                       const unsigned short* __restrict__ Wq,
                       const unsigned short* __restrict__ Wk,
                       const unsigned short* __restrict__ Wv,
                       const float* __restrict__ bq,
                       const float* __restrict__ bk,
                       const float* __restrict__ bv,
                       unsigned short* __restrict__ qb,
                       unsigned short* __restrict__ kb,
                       unsigned short* __restrict__ vtb) {
    __shared__ __align__(16) unsigned short abuf[4 * 128 * 8];
    __shared__ __align__(16) unsigned short bbuf[4 * 128 * 8];
    const int tid = threadIdx.x, lane = tid & 63, w = tid >> 6;
    const int r = lane & 15, quad = lane >> 4;
    const int nt = blockIdx.x, mt = blockIdx.y, z = blockIdx.z;
    const unsigned short* W  = (z == 0) ? Wq : (z == 1) ? Wk : Wv;
    const float*          Bv = (z == 0) ? bq : (z == 1) ? bk : bv;
    unsigned short*     outp = (z == 0) ? qb : (z == 1) ? kb : vtb;

    const int c0 = w * 64 + lane, c1 = c0 + 256;
    const unsigned short* xs0 = X + (mt * 128 + (c0 & 127)) * 768 + (c0 >> 7) * 8;
    const unsigned short* xs1 = X + (mt * 128 + (c1 & 127)) * 768 + (c1 >> 7) * 8;
    const unsigned short* ws0 = W + (nt * 128 + (c0 & 127)) * 768 + (c0 >> 7) * 8;
    const unsigned short* ws1 = W + (nt * 128 + (c1 & 127)) * 768 + (c1 >> 7) * 8;

    const int wr = (w & 1) * 64, wc = (w >> 1) * 64;
    f32x4 acc[4][4] = {};
    for (int kt = 0; kt < 24; ++kt) {
        gl_lds16(xs0 + kt * 32, &abuf[w * 512]);
        gl_lds16(xs1 + kt * 32, &abuf[2048 + w * 512]);
        gl_lds16(ws0 + kt * 32, &bbuf[w * 512]);
        gl_lds16(ws1 + kt * 32, &bbuf[2048 + w * 512]);
        __syncthreads();
        bf16x8 af[4], bfr[4];
#pragma unroll
        for (int i = 0; i < 4; ++i)
            af[i] = *(const bf16x8*)&abuf[(quad * 128 + wr + i * 16 + r) * 8];
#pragma unroll
        for (int j = 0; j < 4; ++j)
            bfr[j] = *(const bf16x8*)&bbuf[(quad * 128 + wc + j * 16 + r) * 8];
#pragma unroll
        for (int i = 0; i < 4; ++i)
#pragma unroll
            for (int j = 0; j < 4; ++j)
                acc[i][j] = __builtin_amdgcn_mfma_f32_16x16x32_bf16(af[i], bfr[j], acc[i][j], 0, 0, 0);
        __syncthreads();
    }
#pragma unroll
    for (int j = 0; j < 4; ++j) {
        const int n = nt * 128 + wc + j * 16 + r;
        const float bias = Bv[n];
        const int nhi = n >> 6, nlo = n & 63;
#pragma unroll
        for (int i = 0; i < 4; ++i) {
#pragma unroll
            for (int reg = 0; reg < 4; ++reg) {
                const unsigned short hv = f2b(acc[i][j][reg] + bias);
                if (z < 2) {
                    const int m = mt * 128 + wr + i * 16 + quad * 4 + reg;
                    outp[(nhi * 4096 + m) * 64 + nlo] = hv;
                } else {
                    // tile = w&1, kk = i*16+quad*4+reg
                    const int mp = mt * 128 + i * 32 + quad * 8 + (w & 1) * 4 + reg;
                    outp[(nhi * 64 + nlo) * 4096 + mp] = hv;
                }
            }
        }
    }
}

// ---------------------------------------------------------------------------
// Output projection, 128x128 tile, fp32 row-major out. M=4096, N=768, K=768.
// ---------------------------------------------------------------------------
__launch_bounds__(256, 3)
__global__ void out128(const unsigned short* __restrict__ X,
                       const unsigned short* __restrict__ W,
                       const float* __restrict__ Bv,
                       float* __restrict__ out) {
    __shared__ __align__(16) unsigned short abuf[4 * 128 * 8];
    __shared__ __align__(16) unsigned short bbuf[4 * 128 * 8];
    const int tid = threadIdx.x, lane = tid & 63, w = tid >> 6;
    const int r = lane & 15, quad = lane >> 4;
    const int nt = blockIdx.x, mt = blockIdx.y;

    const int c0 = w * 64 + lane, c1 = c0 + 256;
    const unsigned short* xs0 = X + (mt * 128 + (c0 & 127)) * 768 + (c0 >> 7) * 8;
    const unsigned short* xs1 = X + (mt * 128 + (c1 & 127)) * 768 + (c1 >> 7) * 8;
    const unsigned short* ws0 = W + (nt * 128 + (c0 & 127)) * 768 + (c0 >> 7) * 8;
    const unsigned short* ws1 = W + (nt * 128 + (c1 & 127)) * 768 + (c1 >> 7) * 8;

    const int wr = (w & 1) * 64, wc = (w >> 1) * 64;
    f32x4 acc[4][4] = {};
    for (int kt = 0; kt < 24; ++kt) {
        gl_lds16(xs0 + kt * 32, &abuf[w * 512]);
        gl_lds16(xs1 + kt * 32, &abuf[2048 + w * 512]);
        gl_lds16(ws0 + kt * 32, &bbuf[w * 512]);
        gl_lds16(ws1 + kt * 32, &bbuf[2048 + w * 512]);
        __syncthreads();
        bf16x8 af[4], bfr[4];
#pragma unroll
        for (int i = 0; i < 4; ++i)
            af[i] = *(const bf16x8*)&abuf[(quad * 128 + wr + i * 16 + r) * 8];
#pragma unroll
        for (int j = 0; j < 4; ++j)
            bfr[j] = *(const bf16x8*)&bbuf[(quad * 128 + wc + j * 16 + r) * 8];
#pragma unroll
        for (int i = 0; i < 4; ++i)
#pragma unroll
            for (int j = 0; j < 4; ++j)
                acc[i][j] = __builtin_amdgcn_mfma_f32_16x16x32_bf16(af[i], bfr[j], acc[i][j], 0, 0, 0);
        __syncthreads();
    }
#pragma unroll
    for (int j = 0; j < 4; ++j) {
        const int n = nt * 128 + wc + j * 16 + r;
        const float bias = Bv[n];
#pragma unroll
        for (int i = 0; i < 4; ++i) {
#pragma unroll
            for (int reg = 0; reg < 4; ++reg) {
                const int m = mt * 128 + wr + i * 16 + quad * 4 + reg;
                out[m * 768 + n] = acc[i][j][reg] + bias;
            }
        }
    }
}

// ---------------------------------------------------------------------------
// rel_w: per (head, a=query-col) 64x64x64 GEMM; queries t = m*64 + a,
// B[n][c] = rpw[a - n + 63][c]. Output rw[h][qtoken][kj].
// ---------------------------------------------------------------------------
__launch_bounds__(256, 4)
__global__ void relw(const unsigned short* __restrict__ qbuf,
                     const unsigned short* __restrict__ rpw,
                     unsigned short* __restrict__ rw) {
    __shared__ __align__(16) unsigned short abuf[8 * 64 * 8];
    __shared__ __align__(16) unsigned short bbuf[8 * 64 * 8];
    const int tid = threadIdx.x;
    const int lane = tid & 63, w = tid >> 6;
    const int r = lane & 15, quad = lane >> 4;
    const int a = blockIdx.x, h = blockIdx.y;

#pragma unroll
    for (int gg = 0; gg < 2; ++gg) {
        const int g = w * 2 + gg;
        gl_lds16(qbuf + (h * 4096 + lane * 64 + a) * 64 + g * 8, &abuf[g * 512]);
        gl_lds16(rpw + (a - lane + 63) * 64 + g * 8, &bbuf[g * 512]);
    }
    __syncthreads();

    f32x4 acc[4] = {};
#pragma unroll
    for (int s = 0; s < 2; ++s) {
        bf16x8 af = *(const bf16x8*)&abuf[((s * 4 + quad) * 64 + w * 16 + r) * 8];
#pragma unroll
        for (int j = 0; j < 4; ++j) {
            bf16x8 bfr = *(const bf16x8*)&bbuf[((s * 4 + quad) * 64 + j * 16 + r) * 8];
            acc[j] = __builtin_amdgcn_mfma_f32_16x16x32_bf16(af, bfr, acc[j], 0, 0, 0);
        }
    }
#pragma unroll
    for (int j = 0; j < 4; ++j) {
#pragma unroll
        for (int reg = 0; reg < 4; ++reg) {
            const int m = w * 16 + quad * 4 + reg, n = j * 16 + r;
            rw[((h * 4096 + m * 64 + a)) * 64 + n] = f2b(acc[j][reg]);
        }
    }
}

// ---------------------------------------------------------------------------
// Flash attention, S^T form. Block = 64-query tile; wave w owns keys
// [w*16, w*16+16) of every key tile; loop over 32 pairs of key tiles.
// ---------------------------------------------------------------------------
__launch_bounds__(256, 3)
__global__ void attn(const unsigned short* __restrict__ qbuf,
                     const unsigned short* __restrict__ kbuf,
                     const unsigned short* __restrict__ vtbuf,
                     const unsigned short* __restrict__ rph,
                     const unsigned short* __restrict__ rwb,
                     unsigned short* __restrict__ aout) {
    // LDS arena: [0,16384) skb (2 tiles x 512 swizzled 16B cells)
    //            [16384,32768) svb (1024 swizzled cells, one pair)
    //            [32768,41216) srh [64][66] bf16
    //            [41216,42240) lbuf [4][4][16] f32
    //            epilogue: obuf [64][66] f32 reuses [0,16896)
    __shared__ __align__(16) char lds[42240];
    unsigned short* skb = (unsigned short*)lds;
    unsigned short* svb = (unsigned short*)(lds + 16384);
    unsigned short* srh = (unsigned short*)(lds + 32768);
    float* lbuf = (float*)(lds + 41216);
    float* obuf = (float*)lds;

    const int tid = threadIdx.x, lane = tid & 63, w = tid >> 6;
    const int r = lane & 15, quad = lane >> 4;
    const int qt = blockIdx.x, h = blockIdx.y;
    const float L2E = 1.44269504f;

    // ---- prologue: Q^T B-frags (registers, whole kernel)
    bf16x8 qf[4][2];
#pragma unroll
    for (int jn = 0; jn < 4; ++jn)
#pragma unroll
        for (int s2 = 0; s2 < 2; ++s2)
            qf[jn][s2] = *(const bf16x8*)(qbuf +
                (h * 4096 + qt * 64 + jn * 16 + r) * 64 + s2 * 32 + quad * 8);

    // rel_w raw bf16 pairs: [q = jn*16+r][kj = w*16+quad*4 + 0..3]
    u32x2 rwraw[4];
#pragma unroll
    for (int jn = 0; jn < 4; ++jn)
        rwraw[jn] = *(const u32x2*)(rwb +
            (h * 4096 + qt * 64 + jn * 16 + r) * 64 + w * 16 + quad * 4);

    // rel_h via MFMA: A = gathered Rh rows (ki = w*16 + m), B = Q^T -> srh[ki][q]
    {
        bf16x8 rf[2];
#pragma unroll
        for (int s2 = 0; s2 < 2; ++s2)
            rf[s2] = *(const bf16x8*)(rph +
                (qt - (w * 16 + r) + 63) * 64 + s2 * 32 + quad * 8);
#pragma unroll
        for (int jn = 0; jn < 4; ++jn) {
            f32x4 ra = {};
            ra = __builtin_amdgcn_mfma_f32_16x16x32_bf16(rf[0], qf[jn][0], ra, 0, 0, 0);
            ra = __builtin_amdgcn_mfma_f32_16x16x32_bf16(rf[1], qf[jn][1], ra, 0, 0, 0);
#pragma unroll
            for (int reg = 0; reg < 4; ++reg)
                srh[(w * 16 + quad * 4 + reg) * 66 + jn * 16 + r] = f2b(ra[reg]);
        }
    }

    // loop-invariant swizzled LDS read offsets (bytes)
    int kfo[2], vfo[4];
#pragma unroll
    for (int s2 = 0; s2 < 2; ++s2) {
        const int kk = w * 16 + r, ch = s2 * 4 + quad;
        kfo[s2] = (kk * 8 + ((ch + kk) & 7)) * 16;
    }
#pragma unroll
    for (int im = 0; im < 4; ++im) {
        const int d = im * 16 + r, kc = w * 4 + quad;
        vfo[im] = (d * 16 + ((kc + d) & 15)) * 16;
    }
    // staging source offsets (elements, lane-dependent, loop-invariant)
    int koff[2], voff[4];
#pragma unroll
    for (int gg = 0; gg < 2; ++gg) {
        const int kk = (w * 2 + gg) * 8 + (lane >> 3);
        const int ch = ((lane & 7) - kk) & 7;
        koff[gg] = kk * 64 + ch * 8;
    }
#pragma unroll
    for (int gg = 0; gg < 4; ++gg) {
        const int d = w * 16 + gg * 4 + quad;
        const int kc = (r - d) & 15;
        voff[gg] = (h * 64 + d) * 4096 + kc * 8;
    }
    const unsigned short* kpair = kbuf + h * 4096 * 64;  // + T*8192 elements
    float lsum[4] = {0.f, 0.f, 0.f, 0.f};
    f32x4 oacc[4][4] = {};
    __syncthreads();  // srh ready

    // ---- main loop over 32 key-tile pairs
#pragma unroll 1
    for (int T = 0; T < 32; ++T) {
        // stage K (2 tiles, swizzled) + V (pair, swizzled)
#pragma unroll
        for (int e = 0; e < 2; ++e)
#pragma unroll
            for (int gg = 0; gg < 2; ++gg)
                gl_lds16(kpair + T * 8192 + e * 4096 + koff[gg],
                         lds + e * 8192 + (w * 2 + gg) * 1024);
#pragma unroll
        for (int gg = 0; gg < 4; ++gg)
            gl_lds16(vtbuf + T * 128 + voff[gg],
                     lds + 16384 + (w * 4 + gg) * 1024);
        __syncthreads();

        union { unsigned int u[4]; bf16x8 v; } pb[4];
#pragma unroll
        for (int e = 0; e < 2; ++e) {
            const int t = T * 2 + e;
            bf16x8 kf0 = *(const bf16x8*)(lds + e * 8192 + kfo[0]);
            bf16x8 kf1 = *(const bf16x8*)(lds + e * 8192 + kfo[1]);
            float rh[4];
#pragma unroll
            for (int jn = 0; jn < 4; ++jn)
                rh[jn] = b2f(srh[t * 66 + jn * 16 + r]);
#pragma unroll
            for (int jn = 0; jn < 4; ++jn) {
                f32x4 sa = {};
                sa = __builtin_amdgcn_mfma_f32_16x16x32_bf16(kf0, qf[jn][0], sa, 0, 0, 0);
                sa = __builtin_amdgcn_mfma_f32_16x16x32_bf16(kf1, qf[jn][1], sa, 0, 0, 0);
                const float p0 = exp2f(fmaf(sa[0], 0.125f, rh[jn] + lo16f(rwraw[jn].x)) * L2E);
                const float p1 = exp2f(fmaf(sa[1], 0.125f, rh[jn] + hi16f(rwraw[jn].x)) * L2E);
                const float p2 = exp2f(fmaf(sa[2], 0.125f, rh[jn] + lo16f(rwraw[jn].y)) * L2E);
                const float p3 = exp2f(fmaf(sa[3], 0.125f, rh[jn] + hi16f(rwraw[jn].y)) * L2E);
                lsum[jn] += (p0 + p1) + (p2 + p3);
                pb[jn].u[e * 2 + 0] = __builtin_amdgcn_perm(fbits(p1), fbits(p0), 0x07060302);
                pb[jn].u[e * 2 + 1] = __builtin_amdgcn_perm(fbits(p3), fbits(p2), 0x07060302);
            }
        }
        // PV: O^T += V * P^T (K=32 over the pair's interleaved keys)
#pragma unroll
        for (int im = 0; im < 4; ++im) {
            bf16x8 vf = *(const bf16x8*)(lds + 16384 + vfo[im]);
#pragma unroll
            for (int jn = 0; jn < 4; ++jn)
                oacc[im][jn] = __builtin_amdgcn_mfma_f32_16x16x32_bf16(vf, pb[jn].v, oacc[im][jn], 0, 0, 0);
        }
        __syncthreads();
    }

    // ---- epilogue: cross-wave reduce O^T and l, normalize, store
    for (int i = tid; i < 4224; i += 256) obuf[i] = 0.f;
#pragma unroll
    for (int jn = 0; jn < 4; ++jn) {
        lsum[jn] += __shfl_xor(lsum[jn], 16);
        lsum[jn] += __shfl_xor(lsum[jn], 32);
    }
    if (quad == 0) {
#pragma unroll
        for (int jn = 0; jn < 4; ++jn) lbuf[(w * 4 + jn) * 16 + r] = lsum[jn];
    }
    __syncthreads();
#pragma unroll
    for (int im = 0; im < 4; ++im)
#pragma unroll
        for (int jn = 0; jn < 4; ++jn)
#pragma unroll
            for (int reg = 0; reg < 4; ++reg)
                atomicAdd(&obuf[(jn * 16 + r) * 66 + im * 16 + quad * 4 + reg],
                          oacc[im][jn][reg]);
    __syncthreads();
    {
        const int q = tid >> 2, dg = tid & 3;
        const float l = lbuf[(q >> 4) * 16 + (q & 15)] +
                        lbuf[(4 + (q >> 4)) * 16 + (q & 15)] +
                        lbuf[(8 + (q >> 4)) * 16 + (q & 15)] +
                        lbuf[(12 + (q >> 4)) * 16 + (q & 15)];
        const float inv = 1.f / l;
        unsigned int ov[8];
#pragma unroll
        for (int i = 0; i < 8; ++i) {
            const float a = obuf[q * 66 + dg * 16 + 2 * i] * inv;
            const float b = obuf[q * 66 + dg * 16 + 2 * i + 1] * inv;
            ov[i] = (unsigned int)f2b(a) | ((unsigned int)f2b(b) << 16);
        }
        unsigned short* dst = aout + (qt * 64 + q) * 768 + h * 64 + dg * 16;
        u32x4 w0 = {ov[0], ov[1], ov[2], ov[3]};
        u32x4 w1 = {ov[4], ov[5], ov[6], ov[7]};
        *(u32x4*)dst = w0;
        *(u32x4*)(dst + 8) = w1;
    }
}

// ---------------------------------------------------------------------------
extern "C" void kernel_launch(void* const* d_in, const int* in_sizes, int n_in,
                              void* d_out, int out_size, void* d_ws, size_t ws_size,
                              hipStream_t stream) {
    const float* hs  = (const float*)d_in[0];
    const float* wq  = (const float*)d_in[1];
    const float* bq  = (const float*)d_in[2];
    const float* wk  = (const float*)d_in[3];
    const float* bk  = (const float*)d_in[4];
    const float* wv  = (const float*)d_in[5];
    const float* bv  = (const float*)d_in[6];
    const float* wo  = (const float*)d_in[7];
    const float* bo  = (const float*)d_in[8];
    const float* rph = (const float*)d_in[9];
    const float* rpw = (const float*)d_in[10];

    unsigned short* ws = (unsigned short*)d_ws;
    const int HS = 3145728, WN = 589824, RP = 8128;
    const int HB = 12 * 4096 * 64;
    unsigned short* hsb  = ws;
    unsigned short* wqb  = hsb  + HS;
    unsigned short* wkb  = wqb  + WN;
    unsigned short* wvb  = wkb  + WN;
    unsigned short* wob  = wvb  + WN;
    unsigned short* rphb = wob  + WN;
    unsigned short* rpwb = rphb + RP;
    unsigned short* qb   = rpwb + RP;          // q   [h][t][d]
    unsigned short* kb   = qb   + HB;          // k   [h][t][d]
    unsigned short* vtb  = kb   + HB;          // v^T [h][d][t], pair-interleaved
    unsigned short* rwb  = vtb  + HB;          // rel_w [h][t][kj]
    unsigned short* ab   = rwb  + HB;          // attn out [t][768]

    cvt_bf16<<<dim3((1380320 + 255) / 256), 256, 0, stream>>>(
        hs, wq, wk, wv, wo, rph, rpw, hsb);
    qkv128<<<dim3(6, 32, 3), 256, 0, stream>>>(
        hsb, wqb, wkb, wvb, bq, bk, bv, qb, kb, vtb);
    relw<<<dim3(64, 12), 256, 0, stream>>>(qb, rpwb, rwb);
    attn<<<dim3(64, 12), 256, 0, stream>>>(qb, kb, vtb, rphb, rwb, ab);
    out128<<<dim3(6, 32), 256, 0, stream>>>(ab, wob, bo, (float*)d_out);
}

// Round 7
// 271.746 us; speedup vs baseline: 1.3295x; 1.3295x over previous
//
#include <hip/hip_runtime.h>

// ---------------------------------------------------------------------------
// SAM vision attention (B=1, H=W=64, C=768, 12 heads x hd=64). fp32 I/O.
// cvt -> QKV proj (128-tile) -> rel_h/rel_w -> flash attn -> out proj
// MFMA v_mfma_f32_16x16x32_bf16 layouts (guide-verified m89/m91):
//   A/B frag: [m|n = lane&15][k = (lane>>4)*8 + j]   (8 bf16 / lane, b128)
//   C/D     : col = lane&15, row = (lane>>4)*4 + reg (4 f32 / lane)
// R7: attn/relk reverted to the R4-measured versions (126 us attn). qkv z==2
// (v^T) epilogue now goes through an LDS transpose with XOR swizzle and does
// coalesced b128 global stores (was: 64 scalar 2B stores/thread at 8KB stride
// -> massive write-transaction amplification).
// ---------------------------------------------------------------------------

typedef __attribute__((ext_vector_type(8))) short bf16x8;
typedef __attribute__((ext_vector_type(4))) float f32x4;
typedef __attribute__((ext_vector_type(4))) short s16x4;
typedef __attribute__((ext_vector_type(2))) unsigned int u32x2;

__device__ __forceinline__ float b2f(unsigned short h) {
    union { unsigned int u; float f; } v; v.u = ((unsigned int)h) << 16; return v.f;
}
__device__ __forceinline__ unsigned short f2b(float f) {
    union { float f; unsigned int u; } v; v.f = f;
    unsigned int r = v.u + 0x7FFFu + ((v.u >> 16) & 1u);  // RNE
    return (unsigned short)(r >> 16);
}
__device__ __forceinline__ void gl_lds16(const void* g, void* l) {
    __builtin_amdgcn_global_load_lds(
        (const __attribute__((address_space(1))) void*)g,
        (__attribute__((address_space(3))) void*)l, 16, 0, 0);
}

// ---------------------------------------------------------------------------
// fp32 -> bf16 bulk convert into one contiguous region (quad-indexed).
// ---------------------------------------------------------------------------
__global__ __launch_bounds__(256) void cvt_bf16(
        const float* __restrict__ hs, const float* __restrict__ wq,
        const float* __restrict__ wk, const float* __restrict__ wv,
        const float* __restrict__ wo, const float* __restrict__ rph,
        const float* __restrict__ rpw, unsigned short* __restrict__ dst) {
    const int idx = blockIdx.x * 256 + threadIdx.x;
    if (idx >= 1380320) return;
    const float* src;
    int off;
    if      (idx < 786432)  { src = hs;  off = idx; }
    else if (idx < 933888)  { src = wq;  off = idx - 786432; }
    else if (idx < 1081344) { src = wk;  off = idx - 933888; }
    else if (idx < 1228800) { src = wv;  off = idx - 1081344; }
    else if (idx < 1376256) { src = wo;  off = idx - 1228800; }
    else if (idx < 1378288) { src = rph; off = idx - 1376256; }
    else                    { src = rpw; off = idx - 1378288; }
    const float4 v = ((const float4*)src)[off];
    s16x4 o;
    o[0] = (short)f2b(v.x); o[1] = (short)f2b(v.y);
    o[2] = (short)f2b(v.z); o[3] = (short)f2b(v.w);
    *(s16x4*)(dst + (size_t)idx * 4) = o;
}

// ---------------------------------------------------------------------------
// Fused QKV projection, 128x128 tile. M=4096, N=768 per z, K=768, BK=32.
// z: 0->q [n>>6][m][n&63], 1->k same, 2->v^T token-PERMUTED: within each
// 64-token tile, token kk = i*16+quad*4+reg stored at slot (quad*4+reg)*4+i.
// v^T stored via LDS transpose -> coalesced b128 writes.
// ---------------------------------------------------------------------------
__launch_bounds__(256, 3)
__global__ void qkv128(const unsigned short* __restrict__ X,
                       const unsigned short* __restrict__ Wq,
                       const unsigned short* __restrict__ Wk,
                       const unsigned short* __restrict__ Wv,
                       const float* __restrict__ bq,
                       const float* __restrict__ bk,
                       const float* __restrict__ bv,
                       unsigned short* __restrict__ qb,
                       unsigned short* __restrict__ kb,
                       unsigned short* __restrict__ vtb) {
    __shared__ __align__(16) unsigned short sarena[8192];  // abuf | bbuf, 16 KB
    unsigned short* abuf = sarena;
    unsigned short* bbuf = sarena + 4096;
    const int tid = threadIdx.x, lane = tid & 63, w = tid >> 6;
    const int r = lane & 15, quad = lane >> 4;
    const int nt = blockIdx.x, mt = blockIdx.y, z = blockIdx.z;
    const unsigned short* W  = (z == 0) ? Wq : (z == 1) ? Wk : Wv;
    const float*          Bv = (z == 0) ? bq : (z == 1) ? bk : bv;
    unsigned short*     outp = (z == 0) ? qb : (z == 1) ? kb : vtb;

    const int c0 = w * 64 + lane, c1 = c0 + 256;
    const unsigned short* xs0 = X + (mt * 128 + (c0 & 127)) * 768 + (c0 >> 7) * 8;
    const unsigned short* xs1 = X + (mt * 128 + (c1 & 127)) * 768 + (c1 >> 7) * 8;
    const unsigned short* ws0 = W + (nt * 128 + (c0 & 127)) * 768 + (c0 >> 7) * 8;
    const unsigned short* ws1 = W + (nt * 128 + (c1 & 127)) * 768 + (c1 >> 7) * 8;

    const int wr = (w & 1) * 64, wc = (w >> 1) * 64;
    f32x4 acc[4][4] = {};
    for (int kt = 0; kt < 24; ++kt) {
        gl_lds16(xs0 + kt * 32, &abuf[w * 512]);
        gl_lds16(xs1 + kt * 32, &abuf[2048 + w * 512]);
        gl_lds16(ws0 + kt * 32, &bbuf[w * 512]);
        gl_lds16(ws1 + kt * 32, &bbuf[2048 + w * 512]);
        __syncthreads();
        bf16x8 af[4], bfr[4];
#pragma unroll
        for (int i = 0; i < 4; ++i)
            af[i] = *(const bf16x8*)&abuf[(quad * 128 + wr + i * 16 + r) * 8];
#pragma unroll
        for (int j = 0; j < 4; ++j)
            bfr[j] = *(const bf16x8*)&bbuf[(quad * 128 + wc + j * 16 + r) * 8];
#pragma unroll
        for (int i = 0; i < 4; ++i)
#pragma unroll
            for (int j = 0; j < 4; ++j)
                acc[i][j] = __builtin_amdgcn_mfma_f32_16x16x32_bf16(af[i], bfr[j], acc[i][j], 0, 0, 0);
        __syncthreads();
    }
    if (z < 2) {
#pragma unroll
        for (int j = 0; j < 4; ++j) {
            const int n = nt * 128 + wc + j * 16 + r;
            const float bias = Bv[n];
            const int nhi = n >> 6, nlo = n & 63;
#pragma unroll
            for (int i = 0; i < 4; ++i) {
#pragma unroll
                for (int reg = 0; reg < 4; ++reg) {
                    const int m = mt * 128 + wr + i * 16 + quad * 4 + reg;
                    outp[(nhi * 4096 + m) * 64 + nlo] = f2b(acc[i][j][reg] + bias);
                }
            }
        }
    } else {
        // v^T via LDS transpose. Arena reused as [64 n][128 tok] bf16 (16 KB),
        // tok XOR-swizzled by ((n&7)<<4) to spread write banks.
        // Token slot for kk=i*16+quad*4+reg is wr + (quad*4+reg)*4 + i: the
        // four i values are consecutive -> one b64 packed write per (j,reg).
#pragma unroll
        for (int pass = 0; pass < 2; ++pass) {
            if ((w >> 1) == pass) {
#pragma unroll
                for (int j = 0; j < 4; ++j) {
                    const int n_l = j * 16 + r;  // row within this 64-wide half
                    const float bias = Bv[nt * 128 + pass * 64 + n_l];
                    const int sw = (n_l & 7) << 4;
#pragma unroll
                    for (int reg = 0; reg < 4; ++reg) {
                        const int tokb = (wr + (quad * 4 + reg) * 4) ^ sw;
                        u32x2 d2;
                        d2.x = (unsigned int)f2b(acc[0][j][reg] + bias)
                             | ((unsigned int)f2b(acc[1][j][reg] + bias) << 16);
                        d2.y = (unsigned int)f2b(acc[2][j][reg] + bias)
                             | ((unsigned int)f2b(acc[3][j][reg] + bias) << 16);
                        *(u32x2*)&sarena[n_l * 128 + tokb] = d2;
                    }
                }
            }
            __syncthreads();
            // cooperative coalesced store: 16 consecutive threads = 256 B run
#pragma unroll
            for (int c = 0; c < 4; ++c) {
                const int u = c * 256 + tid;
                const int n_l = u >> 4, g = u & 15;
                const int phys = n_l * 128 + ((g * 8) ^ ((n_l & 7) << 4));
                bf16x8 val = *(const bf16x8*)&sarena[phys];
                *(bf16x8*)&outp[(size_t)(nt * 128 + pass * 64 + n_l) * 4096
                                + mt * 128 + g * 8] = val;
            }
            __syncthreads();
        }
    }
}

// ---------------------------------------------------------------------------
// Output projection, 128x128 tile, fp32 row-major out. M=4096, N=768, K=768.
// ---------------------------------------------------------------------------
__launch_bounds__(256, 3)
__global__ void out128(const unsigned short* __restrict__ X,
                       const unsigned short* __restrict__ W,
                       const float* __restrict__ Bv,
                       float* __restrict__ out) {
    __shared__ __align__(16) unsigned short abuf[4 * 128 * 8];
    __shared__ __align__(16) unsigned short bbuf[4 * 128 * 8];
    const int tid = threadIdx.x, lane = tid & 63, w = tid >> 6;
    const int r = lane & 15, quad = lane >> 4;
    const int nt = blockIdx.x, mt = blockIdx.y;

    const int c0 = w * 64 + lane, c1 = c0 + 256;
    const unsigned short* xs0 = X + (mt * 128 + (c0 & 127)) * 768 + (c0 >> 7) * 8;
    const unsigned short* xs1 = X + (mt * 128 + (c1 & 127)) * 768 + (c1 >> 7) * 8;
    const unsigned short* ws0 = W + (nt * 128 + (c0 & 127)) * 768 + (c0 >> 7) * 8;
    const unsigned short* ws1 = W + (nt * 128 + (c1 & 127)) * 768 + (c1 >> 7) * 8;

    const int wr = (w & 1) * 64, wc = (w >> 1) * 64;
    f32x4 acc[4][4] = {};
    for (int kt = 0; kt < 24; ++kt) {
        gl_lds16(xs0 + kt * 32, &abuf[w * 512]);
        gl_lds16(xs1 + kt * 32, &abuf[2048 + w * 512]);
        gl_lds16(ws0 + kt * 32, &bbuf[w * 512]);
        gl_lds16(ws1 + kt * 32, &bbuf[2048 + w * 512]);
        __syncthreads();
        bf16x8 af[4], bfr[4];
#pragma unroll
        for (int i = 0; i < 4; ++i)
            af[i] = *(const bf16x8*)&abuf[(quad * 128 + wr + i * 16 + r) * 8];
#pragma unroll
        for (int j = 0; j < 4; ++j)
            bfr[j] = *(const bf16x8*)&bbuf[(quad * 128 + wc + j * 16 + r) * 8];
#pragma unroll
        for (int i = 0; i < 4; ++i)
#pragma unroll
            for (int j = 0; j < 4; ++j)
                acc[i][j] = __builtin_amdgcn_mfma_f32_16x16x32_bf16(af[i], bfr[j], acc[i][j], 0, 0, 0);
        __syncthreads();
    }
#pragma unroll
    for (int j = 0; j < 4; ++j) {
        const int n = nt * 128 + wc + j * 16 + r;
        const float bias = Bv[n];
#pragma unroll
        for (int i = 0; i < 4; ++i) {
#pragma unroll
            for (int reg = 0; reg < 4; ++reg) {
                const int m = mt * 128 + wr + i * 16 + quad * 4 + reg;
                out[m * 768 + n] = acc[i][j][reg] + bias;
            }
        }
    }
}

// ---------------------------------------------------------------------------
// rel_h / rel_w: per (head, a) 64x64x64 GEMM against gathered rel_pos rows.
// mode 0 (rel_h): a = query image-row, tokens t = a*64 + m.
// mode 1 (rel_w): a = query image-col, tokens t = m*64 + a.
// ---------------------------------------------------------------------------
__launch_bounds__(256, 4)
__global__ void relk(const unsigned short* __restrict__ qbuf,
                     const unsigned short* __restrict__ rph,
                     const unsigned short* __restrict__ rpw,
                     unsigned short* __restrict__ rh,
                     unsigned short* __restrict__ rw) {
    __shared__ __align__(16) unsigned short abuf[8 * 64 * 8];
    __shared__ __align__(16) unsigned short bbuf[8 * 64 * 8];
    const int tid = threadIdx.x;
    const int lane = tid & 63, w = tid >> 6;
    const int r = lane & 15, quad = lane >> 4;
    const int a = blockIdx.x, h = blockIdx.y, mode = blockIdx.z;
    const unsigned short* rp = mode ? rpw : rph;

#pragma unroll
    for (int gg = 0; gg < 2; ++gg) {
        const int g = w * 2 + gg;
        const int arow = mode ? (h * 4096 + lane * 64 + a) : (h * 4096 + a * 64 + lane);
        gl_lds16(qbuf + arow * 64 + g * 8, &abuf[g * 512]);
        const int bidx = a - lane + 63;
        gl_lds16(rp + bidx * 64 + g * 8, &bbuf[g * 512]);
    }
    __syncthreads();

    f32x4 acc[4] = {};
#pragma unroll
    for (int s = 0; s < 2; ++s) {
        bf16x8 af = *(const bf16x8*)&abuf[((s * 4 + quad) * 64 + w * 16 + r) * 8];
#pragma unroll
        for (int j = 0; j < 4; ++j) {
            bf16x8 bfr = *(const bf16x8*)&bbuf[((s * 4 + quad) * 64 + j * 16 + r) * 8];
            acc[j] = __builtin_amdgcn_mfma_f32_16x16x32_bf16(af, bfr, acc[j], 0, 0, 0);
        }
    }
    unsigned short* out = mode ? rw : rh;
#pragma unroll
    for (int j = 0; j < 4; ++j) {
#pragma unroll
        for (int reg = 0; reg < 4; ++reg) {
            const int m = w * 16 + quad * 4 + reg, n = j * 16 + r;
            const int t = mode ? (h * 4096 + m * 64 + a) : (h * 4096 + a * 64 + m);
            out[t * 64 + n] = f2b(acc[j][reg]);
        }
    }
}

// ---------------------------------------------------------------------------
// Flash attention (R4-measured version), 64-query tile (4 waves x 16 q),
// 64 key tiles of 64. Fixed softmax reference (m=0). V token-permuted so each
// lane's 4 P values pack into one b64 LDS write; spb stride 72 conflict-free.
// ---------------------------------------------------------------------------
__launch_bounds__(256, 4)
__global__ void attn(const unsigned short* __restrict__ qbuf,
                     const unsigned short* __restrict__ kbuf,
                     const unsigned short* __restrict__ vtbuf,
                     const unsigned short* __restrict__ rh,
                     const unsigned short* __restrict__ rw,
                     unsigned short* __restrict__ aout) {
    __shared__ __align__(16) unsigned short skb[8 * 64 * 8];   // K [d_oct][key][8]
    __shared__ __align__(16) unsigned short svb[8 * 64 * 8];   // V^T [scol_oct][d][8]
    __shared__ __align__(16) unsigned short spb[4 * 16 * 72];  // P, row stride 72
    __shared__ __align__(16) unsigned short srh[8 * 64 * 8];   // rel_h [ki_oct][ql][8]
    const int tid = threadIdx.x;
    const int lane = tid & 63, w = tid >> 6;
    const int r = lane & 15, quad = lane >> 4;
    const int qt = blockIdx.x, h = blockIdx.y;
    const float L2E = 1.44269504f;
    const float SC = 0.125f * L2E;

#pragma unroll
    for (int gg = 0; gg < 2; ++gg) {
        const int g = w * 2 + gg;
        gl_lds16(rh + (h * 4096 + qt * 64 + lane) * 64 + g * 8, &srh[g * 512]);
    }
    float rwL[4][4];  // rel_w * log2e, tile-invariant (kj = key % 64)
    {
        const unsigned short* rwrow = rw + (h * 4096 + qt * 64) * 64;
#pragma unroll
        for (int reg = 0; reg < 4; ++reg) {
            const int ql = w * 16 + quad * 4 + reg;
#pragma unroll
            for (int j = 0; j < 4; ++j)
                rwL[j][reg] = b2f(rwrow[ql * 64 + j * 16 + r]) * L2E;
        }
    }
    bf16x8 qf[2];
    const unsigned short* qrow = qbuf + (h * 4096 + qt * 64 + w * 16 + r) * 64;
    qf[0] = *(const bf16x8*)(qrow + quad * 8);
    qf[1] = *(const bf16x8*)(qrow + 32 + quad * 8);

    float lsum[4] = {0.f, 0.f, 0.f, 0.f};
    f32x4 oacc[4] = {};
    __syncthreads();

    for (int t = 0; t < 64; ++t) {
#pragma unroll
        for (int gg = 0; gg < 2; ++gg) {
            const int g = w * 2 + gg;
            gl_lds16(kbuf + (h * 4096 + t * 64 + lane) * 64 + g * 8, &skb[g * 512]);
            gl_lds16(vtbuf + (h * 64 + lane) * 4096 + t * 64 + g * 8, &svb[g * 512]);
        }
        __syncthreads();

        f32x4 sacc[4] = {};
#pragma unroll
        for (int s = 0; s < 2; ++s) {
#pragma unroll
            for (int j = 0; j < 4; ++j) {
                bf16x8 kf = *(const bf16x8*)&skb[((s * 4 + quad) * 64 + j * 16 + r) * 8];
                sacc[j] = __builtin_amdgcn_mfma_f32_16x16x32_bf16(qf[s], kf, sacc[j], 0, 0, 0);
            }
        }
        float rhL[4];
#pragma unroll
        for (int reg = 0; reg < 4; ++reg) {
            const int ql = w * 16 + quad * 4 + reg;
            rhL[reg] = b2f(srh[((t >> 3) * 64 + ql) * 8 + (t & 7)]) * L2E;
        }
#pragma unroll
        for (int reg = 0; reg < 4; ++reg) {
            unsigned int u[4];
#pragma unroll
            for (int j = 0; j < 4; ++j) {
                const float p = exp2f(fmaf(sacc[j][reg], SC, rhL[reg] + rwL[j][reg]));
                lsum[reg] += p;
                union { float f; unsigned int q; } cv; cv.f = p;
                u[j] = cv.q;
            }
            u32x2 d;
            d.x = __builtin_amdgcn_perm(u[1], u[0], 0x07060302);
            d.y = __builtin_amdgcn_perm(u[3], u[2], 0x07060302);
            *(u32x2*)&spb[w * 1152 + (quad * 4 + reg) * 72 + r * 4] = d;
        }
#pragma unroll
        for (int s = 0; s < 2; ++s) {
            bf16x8 pf = *(const bf16x8*)&spb[w * 1152 + r * 72 + s * 32 + quad * 8];
#pragma unroll
            for (int j = 0; j < 4; ++j) {
                bf16x8 vf = *(const bf16x8*)&svb[((s * 4 + quad) * 64 + j * 16 + r) * 8];
                oacc[j] = __builtin_amdgcn_mfma_f32_16x16x32_bf16(pf, vf, oacc[j], 0, 0, 0);
            }
        }
        __syncthreads();
    }
#pragma unroll
    for (int reg = 0; reg < 4; ++reg) {
        float s = lsum[reg];
        s += __shfl_xor(s, 1);
        s += __shfl_xor(s, 2);
        s += __shfl_xor(s, 4);
        s += __shfl_xor(s, 8);
        const float inv = 1.f / s;
        const int m = qt * 64 + w * 16 + quad * 4 + reg;
#pragma unroll
        for (int j = 0; j < 4; ++j)
            aout[m * 768 + h * 64 + j * 16 + r] = f2b(oacc[j][reg] * inv);
    }
}

// ---------------------------------------------------------------------------
extern "C" void kernel_launch(void* const* d_in, const int* in_sizes, int n_in,
                              void* d_out, int out_size, void* d_ws, size_t ws_size,
                              hipStream_t stream) {
    const float* hs  = (const float*)d_in[0];
    const float* wq  = (const float*)d_in[1];
    const float* bq  = (const float*)d_in[2];
    const float* wk  = (const float*)d_in[3];
    const float* bk  = (const float*)d_in[4];
    const float* wv  = (const float*)d_in[5];
    const float* bv  = (const float*)d_in[6];
    const float* wo  = (const float*)d_in[7];
    const float* bo  = (const float*)d_in[8];
    const float* rph = (const float*)d_in[9];
    const float* rpw = (const float*)d_in[10];

    unsigned short* ws = (unsigned short*)d_ws;
    const int HS = 3145728, WN = 589824, RP = 8128;
    const int HB = 12 * 4096 * 64;
    unsigned short* hsb  = ws;
    unsigned short* wqb  = hsb  + HS;
    unsigned short* wkb  = wqb  + WN;
    unsigned short* wvb  = wkb  + WN;
    unsigned short* wob  = wvb  + WN;
    unsigned short* rphb = wob  + WN;
    unsigned short* rpwb = rphb + RP;
    unsigned short* qb   = rpwb + RP;          // q   [h][t][d]
    unsigned short* kb   = qb   + HB;          // k   [h][t][d]
    unsigned short* vtb  = kb   + HB;          // v^T [h][d][t], token-permuted
    unsigned short* rhb  = vtb  + HB;          // rel_h [h][t][ki]
    unsigned short* rwb  = rhb  + HB;          // rel_w [h][t][kj]
    unsigned short* ab   = rwb  + HB;          // attn out [t][768]

    cvt_bf16<<<dim3((1380320 + 255) / 256), 256, 0, stream>>>(
        hs, wq, wk, wv, wo, rph, rpw, hsb);
    qkv128<<<dim3(6, 32, 3), 256, 0, stream>>>(
        hsb, wqb, wkb, wvb, bq, bk, bv, qb, kb, vtb);
    relk<<<dim3(64, 12, 2), 256, 0, stream>>>(qb, rphb, rpwb, rhb, rwb);
    attn<<<dim3(64, 12), 256, 0, stream>>>(qb, kb, vtb, rhb, rwb, ab);
    out128<<<dim3(6, 32), 256, 0, stream>>>(ab, wob, bo, (float*)d_out);
}

// Round 8
// 270.504 us; speedup vs baseline: 1.3356x; 1.0046x over previous
//
#include <hip/hip_runtime.h>

// ---------------------------------------------------------------------------
// SAM vision attention (B=1, H=W=64, C=768, 12 heads x hd=64). fp32 I/O.
// cvt -> QKV proj (128-tile) -> rel_h/rel_w -> flash attn (split-K, 32 q/wave)
//   -> combine -> out proj
// MFMA v_mfma_f32_16x16x32_bf16 layouts (guide-verified m89/m91):
//   A/B frag: [m|n = lane&15][k = (lane>>4)*8 + j]   (8 bf16 / lane, b128)
//   C/D     : col = lane&15, row = (lane>>4)*4 + reg (4 f32 / lane)
// R8: attn restructured: 128-query blocks (2 qgroups of 16 per wave) so each
// kf/vf b128 LDS read feeds TWO MFMAs (LDS cyc/MFMA 16.5 -> 10.5); fixed-ref
// softmax (m=0) makes partials plain sums -> split-K over key halves keeps
// 768 blocks (3/CU, 12 waves/CU). attn emits f32 (O_num, l) partials;
// combine kernel normalizes into bf16 ab.
// ---------------------------------------------------------------------------

typedef __attribute__((ext_vector_type(8))) short bf16x8;
typedef __attribute__((ext_vector_type(4))) float f32x4;
typedef __attribute__((ext_vector_type(4))) short s16x4;
typedef __attribute__((ext_vector_type(2))) unsigned int u32x2;

__device__ __forceinline__ float b2f(unsigned short h) {
    union { unsigned int u; float f; } v; v.u = ((unsigned int)h) << 16; return v.f;
}
__device__ __forceinline__ unsigned short f2b(float f) {
    union { float f; unsigned int u; } v; v.f = f;
    unsigned int r = v.u + 0x7FFFu + ((v.u >> 16) & 1u);  // RNE
    return (unsigned short)(r >> 16);
}
__device__ __forceinline__ void gl_lds16(const void* g, void* l) {
    __builtin_amdgcn_global_load_lds(
        (const __attribute__((address_space(1))) void*)g,
        (__attribute__((address_space(3))) void*)l, 16, 0, 0);
}

// ---------------------------------------------------------------------------
// fp32 -> bf16 bulk convert into one contiguous region (quad-indexed).
// ---------------------------------------------------------------------------
__global__ __launch_bounds__(256) void cvt_bf16(
        const float* __restrict__ hs, const float* __restrict__ wq,
        const float* __restrict__ wk, const float* __restrict__ wv,
        const float* __restrict__ wo, const float* __restrict__ rph,
        const float* __restrict__ rpw, unsigned short* __restrict__ dst) {
    const int idx = blockIdx.x * 256 + threadIdx.x;
    if (idx >= 1380320) return;
    const float* src;
    int off;
    if      (idx < 786432)  { src = hs;  off = idx; }
    else if (idx < 933888)  { src = wq;  off = idx - 786432; }
    else if (idx < 1081344) { src = wk;  off = idx - 933888; }
    else if (idx < 1228800) { src = wv;  off = idx - 1081344; }
    else if (idx < 1376256) { src = wo;  off = idx - 1228800; }
    else if (idx < 1378288) { src = rph; off = idx - 1376256; }
    else                    { src = rpw; off = idx - 1378288; }
    const float4 v = ((const float4*)src)[off];
    s16x4 o;
    o[0] = (short)f2b(v.x); o[1] = (short)f2b(v.y);
    o[2] = (short)f2b(v.z); o[3] = (short)f2b(v.w);
    *(s16x4*)(dst + (size_t)idx * 4) = o;
}

// ---------------------------------------------------------------------------
// Fused QKV projection, 128x128 tile. z: 0->q, 1->k [n>>6][m][n&63];
// 2->v^T token-PERMUTED (token kk=i*16+quad*4+reg at slot (quad*4+reg)*4+i),
// stored via LDS transpose with coalesced b128 writes.
// ---------------------------------------------------------------------------
__launch_bounds__(256, 3)
__global__ void qkv128(const unsigned short* __restrict__ X,
                       const unsigned short* __restrict__ Wq,
                       const unsigned short* __restrict__ Wk,
                       const unsigned short* __restrict__ Wv,
                       const float* __restrict__ bq,
                       const float* __restrict__ bk,
                       const float* __restrict__ bv,
                       unsigned short* __restrict__ qb,
                       unsigned short* __restrict__ kb,
                       unsigned short* __restrict__ vtb) {
    __shared__ __align__(16) unsigned short sarena[8192];
    unsigned short* abuf = sarena;
    unsigned short* bbuf = sarena + 4096;
    const int tid = threadIdx.x, lane = tid & 63, w = tid >> 6;
    const int r = lane & 15, quad = lane >> 4;
    const int nt = blockIdx.x, mt = blockIdx.y, z = blockIdx.z;
    const unsigned short* W  = (z == 0) ? Wq : (z == 1) ? Wk : Wv;
    const float*          Bv = (z == 0) ? bq : (z == 1) ? bk : bv;
    unsigned short*     outp = (z == 0) ? qb : (z == 1) ? kb : vtb;

    const int c0 = w * 64 + lane, c1 = c0 + 256;
    const unsigned short* xs0 = X + (mt * 128 + (c0 & 127)) * 768 + (c0 >> 7) * 8;
    const unsigned short* xs1 = X + (mt * 128 + (c1 & 127)) * 768 + (c1 >> 7) * 8;
    const unsigned short* ws0 = W + (nt * 128 + (c0 & 127)) * 768 + (c0 >> 7) * 8;
    const unsigned short* ws1 = W + (nt * 128 + (c1 & 127)) * 768 + (c1 >> 7) * 8;

    const int wr = (w & 1) * 64, wc = (w >> 1) * 64;
    f32x4 acc[4][4] = {};
    for (int kt = 0; kt < 24; ++kt) {
        gl_lds16(xs0 + kt * 32, &abuf[w * 512]);
        gl_lds16(xs1 + kt * 32, &abuf[2048 + w * 512]);
        gl_lds16(ws0 + kt * 32, &bbuf[w * 512]);
        gl_lds16(ws1 + kt * 32, &bbuf[2048 + w * 512]);
        __syncthreads();
        bf16x8 af[4], bfr[4];
#pragma unroll
        for (int i = 0; i < 4; ++i)
            af[i] = *(const bf16x8*)&abuf[(quad * 128 + wr + i * 16 + r) * 8];
#pragma unroll
        for (int j = 0; j < 4; ++j)
            bfr[j] = *(const bf16x8*)&bbuf[(quad * 128 + wc + j * 16 + r) * 8];
#pragma unroll
        for (int i = 0; i < 4; ++i)
#pragma unroll
            for (int j = 0; j < 4; ++j)
                acc[i][j] = __builtin_amdgcn_mfma_f32_16x16x32_bf16(af[i], bfr[j], acc[i][j], 0, 0, 0);
        __syncthreads();
    }
    if (z < 2) {
#pragma unroll
        for (int j = 0; j < 4; ++j) {
            const int n = nt * 128 + wc + j * 16 + r;
            const float bias = Bv[n];
            const int nhi = n >> 6, nlo = n & 63;
#pragma unroll
            for (int i = 0; i < 4; ++i) {
#pragma unroll
                for (int reg = 0; reg < 4; ++reg) {
                    const int m = mt * 128 + wr + i * 16 + quad * 4 + reg;
                    outp[(nhi * 4096 + m) * 64 + nlo] = f2b(acc[i][j][reg] + bias);
                }
            }
        }
    } else {
#pragma unroll
        for (int pass = 0; pass < 2; ++pass) {
            if ((w >> 1) == pass) {
#pragma unroll
                for (int j = 0; j < 4; ++j) {
                    const int n_l = j * 16 + r;
                    const float bias = Bv[nt * 128 + pass * 64 + n_l];
                    const int sw = (n_l & 7) << 4;
#pragma unroll
                    for (int reg = 0; reg < 4; ++reg) {
                        const int tokb = (wr + (quad * 4 + reg) * 4) ^ sw;
                        u32x2 d2;
                        d2.x = (unsigned int)f2b(acc[0][j][reg] + bias)
                             | ((unsigned int)f2b(acc[1][j][reg] + bias) << 16);
                        d2.y = (unsigned int)f2b(acc[2][j][reg] + bias)
                             | ((unsigned int)f2b(acc[3][j][reg] + bias) << 16);
                        *(u32x2*)&sarena[n_l * 128 + tokb] = d2;
                    }
                }
            }
            __syncthreads();
#pragma unroll
            for (int c = 0; c < 4; ++c) {
                const int u = c * 256 + tid;
                const int n_l = u >> 4, g = u & 15;
                const int phys = n_l * 128 + ((g * 8) ^ ((n_l & 7) << 4));
                bf16x8 val = *(const bf16x8*)&sarena[phys];
                *(bf16x8*)&outp[(size_t)(nt * 128 + pass * 64 + n_l) * 4096
                                + mt * 128 + g * 8] = val;
            }
            __syncthreads();
        }
    }
}

// ---------------------------------------------------------------------------
// Output projection, 128x128 tile, fp32 row-major out.
// ---------------------------------------------------------------------------
__launch_bounds__(256, 3)
__global__ void out128(const unsigned short* __restrict__ X,
                       const unsigned short* __restrict__ W,
                       const float* __restrict__ Bv,
                       float* __restrict__ out) {
    __shared__ __align__(16) unsigned short abuf[4 * 128 * 8];
    __shared__ __align__(16) unsigned short bbuf[4 * 128 * 8];
    const int tid = threadIdx.x, lane = tid & 63, w = tid >> 6;
    const int r = lane & 15, quad = lane >> 4;
    const int nt = blockIdx.x, mt = blockIdx.y;

    const int c0 = w * 64 + lane, c1 = c0 + 256;
    const unsigned short* xs0 = X + (mt * 128 + (c0 & 127)) * 768 + (c0 >> 7) * 8;
    const unsigned short* xs1 = X + (mt * 128 + (c1 & 127)) * 768 + (c1 >> 7) * 8;
    const unsigned short* ws0 = W + (nt * 128 + (c0 & 127)) * 768 + (c0 >> 7) * 8;
    const unsigned short* ws1 = W + (nt * 128 + (c1 & 127)) * 768 + (c1 >> 7) * 8;

    const int wr = (w & 1) * 64, wc = (w >> 1) * 64;
    f32x4 acc[4][4] = {};
    for (int kt = 0; kt < 24; ++kt) {
        gl_lds16(xs0 + kt * 32, &abuf[w * 512]);
        gl_lds16(xs1 + kt * 32, &abuf[2048 + w * 512]);
        gl_lds16(ws0 + kt * 32, &bbuf[w * 512]);
        gl_lds16(ws1 + kt * 32, &bbuf[2048 + w * 512]);
        __syncthreads();
        bf16x8 af[4], bfr[4];
#pragma unroll
        for (int i = 0; i < 4; ++i)
            af[i] = *(const bf16x8*)&abuf[(quad * 128 + wr + i * 16 + r) * 8];
#pragma unroll
        for (int j = 0; j < 4; ++j)
            bfr[j] = *(const bf16x8*)&bbuf[(quad * 128 + wc + j * 16 + r) * 8];
#pragma unroll
        for (int i = 0; i < 4; ++i)
#pragma unroll
            for (int j = 0; j < 4; ++j)
                acc[i][j] = __builtin_amdgcn_mfma_f32_16x16x32_bf16(af[i], bfr[j], acc[i][j], 0, 0, 0);
        __syncthreads();
    }
#pragma unroll
    for (int j = 0; j < 4; ++j) {
        const int n = nt * 128 + wc + j * 16 + r;
        const float bias = Bv[n];
#pragma unroll
        for (int i = 0; i < 4; ++i) {
#pragma unroll
            for (int reg = 0; reg < 4; ++reg) {
                const int m = mt * 128 + wr + i * 16 + quad * 4 + reg;
                out[m * 768 + n] = acc[i][j][reg] + bias;
            }
        }
    }
}

// ---------------------------------------------------------------------------
// rel_h / rel_w: per (head, a) 64x64x64 GEMM against gathered rel_pos rows.
// ---------------------------------------------------------------------------
__launch_bounds__(256, 4)
__global__ void relk(const unsigned short* __restrict__ qbuf,
                     const unsigned short* __restrict__ rph,
                     const unsigned short* __restrict__ rpw,
                     unsigned short* __restrict__ rh,
                     unsigned short* __restrict__ rw) {
    __shared__ __align__(16) unsigned short abuf[8 * 64 * 8];
    __shared__ __align__(16) unsigned short bbuf[8 * 64 * 8];
    const int tid = threadIdx.x;
    const int lane = tid & 63, w = tid >> 6;
    const int r = lane & 15, quad = lane >> 4;
    const int a = blockIdx.x, h = blockIdx.y, mode = blockIdx.z;
    const unsigned short* rp = mode ? rpw : rph;

#pragma unroll
    for (int gg = 0; gg < 2; ++gg) {
        const int g = w * 2 + gg;
        const int arow = mode ? (h * 4096 + lane * 64 + a) : (h * 4096 + a * 64 + lane);
        gl_lds16(qbuf + arow * 64 + g * 8, &abuf[g * 512]);
        const int bidx = a - lane + 63;
        gl_lds16(rp + bidx * 64 + g * 8, &bbuf[g * 512]);
    }
    __syncthreads();

    f32x4 acc[4] = {};
#pragma unroll
    for (int s = 0; s < 2; ++s) {
        bf16x8 af = *(const bf16x8*)&abuf[((s * 4 + quad) * 64 + w * 16 + r) * 8];
#pragma unroll
        for (int j = 0; j < 4; ++j) {
            bf16x8 bfr = *(const bf16x8*)&bbuf[((s * 4 + quad) * 64 + j * 16 + r) * 8];
            acc[j] = __builtin_amdgcn_mfma_f32_16x16x32_bf16(af, bfr, acc[j], 0, 0, 0);
        }
    }
    unsigned short* out = mode ? rw : rh;
#pragma unroll
    for (int j = 0; j < 4; ++j) {
#pragma unroll
        for (int reg = 0; reg < 4; ++reg) {
            const int m = w * 16 + quad * 4 + reg, n = j * 16 + r;
            const int t = mode ? (h * 4096 + m * 64 + a) : (h * 4096 + a * 64 + m);
            out[t * 64 + n] = f2b(acc[j][reg]);
        }
    }
}

// ---------------------------------------------------------------------------
// Flash attention, split-K: block = 128-query tile (2 qgroups of 16 / wave),
// split sp covers key tiles sp*32..sp*32+31. kf/vf LDS reads shared across
// both qgroups. Fixed softmax ref (m=0) -> partials are plain sums.
// Emits un-normalized O_num (f32) and l partials.
// ---------------------------------------------------------------------------
__launch_bounds__(256, 3)
__global__ void attn2(const unsigned short* __restrict__ qbuf,
                      const unsigned short* __restrict__ kbuf,
                      const unsigned short* __restrict__ vtbuf,
                      const unsigned short* __restrict__ rhb,
                      const unsigned short* __restrict__ rwb,
                      float* __restrict__ po, float* __restrict__ lp) {
    __shared__ __align__(16) unsigned short skb[4096];   // K [d_oct][key][8]
    __shared__ __align__(16) unsigned short svb[4096];   // V^T [scol_oct][d][8]
    __shared__ __align__(16) unsigned short spb[9216];   // P x2 groups, stride 72
    __shared__ __align__(16) unsigned short srh[8192];   // rel_h [ki_oct][ql0..127][8]
    const int tid = threadIdx.x;
    const int lane = tid & 63, w = tid >> 6;
    const int r = lane & 15, quad = lane >> 4;
    const int qt = blockIdx.x, h = blockIdx.y, sp = blockIdx.z;
    const float L2E = 1.44269504f;
    const float SC = 0.125f * L2E;

    // stage rel_h slice for 128 queries: cell = i*256 + w*64 + lane
#pragma unroll
    for (int i = 0; i < 4; ++i) {
        const int gp = i * 2 + (w >> 1), ql = (w & 1) * 64 + lane;
        gl_lds16(rhb + (h * 4096 + qt * 128 + ql) * 64 + gp * 8,
                 &srh[(i * 256 + w * 64) * 8]);
    }
    // Q frags for both qgroups
    bf16x8 qf[2][2];
#pragma unroll
    for (int g = 0; g < 2; ++g) {
        const unsigned short* qrow =
            qbuf + (h * 4096 + qt * 128 + g * 64 + w * 16 + r) * 64;
        qf[g][0] = *(const bf16x8*)(qrow + quad * 8);
        qf[g][1] = *(const bf16x8*)(qrow + 32 + quad * 8);
    }
    // rel_w * log2e, tile-invariant
    float rwL[2][4][4];
#pragma unroll
    for (int g = 0; g < 2; ++g) {
        const unsigned short* rwrow = rwb + (h * 4096 + qt * 128 + g * 64) * 64;
#pragma unroll
        for (int reg = 0; reg < 4; ++reg) {
            const int ql = w * 16 + quad * 4 + reg;
#pragma unroll
            for (int j = 0; j < 4; ++j)
                rwL[g][j][reg] = b2f(rwrow[ql * 64 + j * 16 + r]) * L2E;
        }
    }
    float lsum[2][4] = {};
    f32x4 oacc[2][4] = {};
    __syncthreads();

    for (int tl = 0; tl < 32; ++tl) {
        const int t = sp * 32 + tl;
#pragma unroll
        for (int gg = 0; gg < 2; ++gg) {
            const int g = w * 2 + gg;
            gl_lds16(kbuf + (h * 4096 + t * 64 + lane) * 64 + g * 8, &skb[g * 512]);
            gl_lds16(vtbuf + (h * 64 + lane) * 4096 + t * 64 + g * 8, &svb[g * 512]);
        }
        __syncthreads();

        // S for both qgroups; kf read once, used twice
        f32x4 s0[4] = {}, s1[4] = {};
#pragma unroll
        for (int s2 = 0; s2 < 2; ++s2) {
#pragma unroll
            for (int j = 0; j < 4; ++j) {
                bf16x8 kf = *(const bf16x8*)&skb[((s2 * 4 + quad) * 64 + j * 16 + r) * 8];
                s0[j] = __builtin_amdgcn_mfma_f32_16x16x32_bf16(qf[0][s2], kf, s0[j], 0, 0, 0);
                s1[j] = __builtin_amdgcn_mfma_f32_16x16x32_bf16(qf[1][s2], kf, s1[j], 0, 0, 0);
            }
        }
        // softmax + pack per qgroup
#pragma unroll
        for (int g = 0; g < 2; ++g) {
            float rh2[4];
#pragma unroll
            for (int reg = 0; reg < 4; ++reg)
                rh2[reg] = b2f(srh[((t >> 3) * 128 + g * 64 + w * 16 + quad * 4 + reg) * 8
                                   + (t & 7)]) * L2E;
#pragma unroll
            for (int reg = 0; reg < 4; ++reg) {
                unsigned int u[4];
#pragma unroll
                for (int j = 0; j < 4; ++j) {
                    const float sv = g ? s1[j][reg] : s0[j][reg];
                    const float p = exp2f(fmaf(sv, SC, rh2[reg] + rwL[g][j][reg]));
                    lsum[g][reg] += p;
                    union { float f; unsigned int q; } cv; cv.f = p;
                    u[j] = cv.q;
                }
                u32x2 d;
                d.x = __builtin_amdgcn_perm(u[1], u[0], 0x07060302);
                d.y = __builtin_amdgcn_perm(u[3], u[2], 0x07060302);
                *(u32x2*)&spb[g * 4608 + w * 1152 + (quad * 4 + reg) * 72 + r * 4] = d;
            }
        }
        // PV: vf read once, used twice
#pragma unroll
        for (int s = 0; s < 2; ++s) {
            bf16x8 pf0 = *(const bf16x8*)&spb[w * 1152 + r * 72 + s * 32 + quad * 8];
            bf16x8 pf1 = *(const bf16x8*)&spb[4608 + w * 1152 + r * 72 + s * 32 + quad * 8];
#pragma unroll
            for (int j = 0; j < 4; ++j) {
                bf16x8 vf = *(const bf16x8*)&svb[((s * 4 + quad) * 64 + j * 16 + r) * 8];
                oacc[0][j] = __builtin_amdgcn_mfma_f32_16x16x32_bf16(pf0, vf, oacc[0][j], 0, 0, 0);
                oacc[1][j] = __builtin_amdgcn_mfma_f32_16x16x32_bf16(pf1, vf, oacc[1][j], 0, 0, 0);
            }
        }
        __syncthreads();
    }
    // epilogue: reduce l across the 16 lanes of each quad-row; store partials
#pragma unroll
    for (int g = 0; g < 2; ++g) {
#pragma unroll
        for (int reg = 0; reg < 4; ++reg) {
            float s = lsum[g][reg];
            s += __shfl_xor(s, 1);
            s += __shfl_xor(s, 2);
            s += __shfl_xor(s, 4);
            s += __shfl_xor(s, 8);
            lsum[g][reg] = s;
        }
    }
    const size_t pbase = ((size_t)(sp * 12 + h) * 4096 + qt * 128);
#pragma unroll
    for (int g = 0; g < 2; ++g) {
        const int qrow = g * 64 + w * 16 + quad * 4;
#pragma unroll
        for (int reg = 0; reg < 4; ++reg) {
#pragma unroll
            for (int j = 0; j < 4; ++j)
                po[(pbase + qrow + reg) * 64 + j * 16 + r] = oacc[g][j][reg];
            if (r == 0) lp[pbase + qrow + reg] = lsum[g][reg];
        }
    }
}

// ---------------------------------------------------------------------------
// Combine split-K partials: ab[t][h*64+d] = (po0+po1)/(l0+l1) as bf16.
// ---------------------------------------------------------------------------
__global__ __launch_bounds__(256) void combine(const float* __restrict__ po,
                                               const float* __restrict__ lp,
                                               unsigned short* __restrict__ ab) {
    const unsigned int idx = blockIdx.x * 256 + threadIdx.x;  // 0..393215
    const unsigned int tok = idx / 96u;
    const unsigned int part = idx - tok * 96u;
    const int c = part * 8, h = c >> 6, d = c & 63;
    const float* p0 = po + ((size_t)h * 4096 + tok) * 64 + d;
    const float* p1 = po + ((size_t)(12 + h) * 4096 + tok) * 64 + d;
    const float inv = 1.f / (lp[h * 4096 + tok] + lp[(12 + h) * 4096 + tok]);
    const float4 a0 = *(const float4*)p0, b0 = *(const float4*)(p0 + 4);
    const float4 a1 = *(const float4*)p1, b1 = *(const float4*)(p1 + 4);
    s16x4 o0, o1;
    o0[0] = (short)f2b((a0.x + a1.x) * inv); o0[1] = (short)f2b((a0.y + a1.y) * inv);
    o0[2] = (short)f2b((a0.z + a1.z) * inv); o0[3] = (short)f2b((a0.w + a1.w) * inv);
    o1[0] = (short)f2b((b0.x + b1.x) * inv); o1[1] = (short)f2b((b0.y + b1.y) * inv);
    o1[2] = (short)f2b((b0.z + b1.z) * inv); o1[3] = (short)f2b((b0.w + b1.w) * inv);
    unsigned short* dst = ab + (size_t)tok * 768 + c;
    *(s16x4*)dst = o0;
    *(s16x4*)(dst + 4) = o1;
}

// ---------------------------------------------------------------------------
extern "C" void kernel_launch(void* const* d_in, const int* in_sizes, int n_in,
                              void* d_out, int out_size, void* d_ws, size_t ws_size,
                              hipStream_t stream) {
    const float* hs  = (const float*)d_in[0];
    const float* wq  = (const float*)d_in[1];
    const float* bq  = (const float*)d_in[2];
    const float* wk  = (const float*)d_in[3];
    const float* bk  = (const float*)d_in[4];
    const float* wv  = (const float*)d_in[5];
    const float* bv  = (const float*)d_in[6];
    const float* wo  = (const float*)d_in[7];
    const float* bo  = (const float*)d_in[8];
    const float* rph = (const float*)d_in[9];
    const float* rpw = (const float*)d_in[10];

    unsigned short* ws = (unsigned short*)d_ws;
    const int HS = 3145728, WN = 589824, RP = 8128;
    const int HB = 12 * 4096 * 64;
    unsigned short* hsb  = ws;
    unsigned short* wqb  = hsb  + HS;
    unsigned short* wkb  = wqb  + WN;
    unsigned short* wvb  = wkb  + WN;
    unsigned short* wob  = wvb  + WN;
    unsigned short* rphb = wob  + WN;
    unsigned short* rpwb = rphb + RP;
    unsigned short* qb   = rpwb + RP;          // q   [h][t][d]
    unsigned short* kb   = qb   + HB;          // k   [h][t][d]
    unsigned short* vtb  = kb   + HB;          // v^T [h][d][t], token-permuted
    unsigned short* rhb  = vtb  + HB;          // rel_h [h][t][ki]
    unsigned short* rwb  = rhb  + HB;          // rel_w [h][t][kj]
    unsigned short* ab   = rwb  + HB;          // attn out [t][768]
    float* po = (float*)(ab + HB);             // O_num partials [2][12][4096][64]
    float* lp = po + 2 * 12 * 4096 * 64;       // l partials [2][12][4096]

    cvt_bf16<<<dim3((1380320 + 255) / 256), 256, 0, stream>>>(
        hs, wq, wk, wv, wo, rph, rpw, hsb);
    qkv128<<<dim3(6, 32, 3), 256, 0, stream>>>(
        hsb, wqb, wkb, wvb, bq, bk, bv, qb, kb, vtb);
    relk<<<dim3(64, 12, 2), 256, 0, stream>>>(qb, rphb, rpwb, rhb, rwb);
    attn2<<<dim3(32, 12, 2), 256, 0, stream>>>(qb, kb, vtb, rhb, rwb, po, lp);
    combine<<<dim3(1536), 256, 0, stream>>>(po, lp, ab);
    out128<<<dim3(6, 32), 256, 0, stream>>>(ab, wob, bo, (float*)d_out);
}

// Round 9
// 248.942 us; speedup vs baseline: 1.4513x; 1.0866x over previous
//
#include <hip/hip_runtime.h>

// ---------------------------------------------------------------------------
// SAM vision attention (B=1, H=W=64, C=768, 12 heads x hd=64). fp32 I/O.
// cvt -> QKV proj (128-tile) -> rel_h/rel_w -> flash attn (split-K, 32 q/wave)
//   -> combine -> out proj
// MFMA v_mfma_f32_16x16x32_bf16 layouts (guide-verified m89/m91):
//   A/B frag: [m|n = lane&15][k = (lane>>4)*8 + j]   (8 bf16 / lane, b128)
//   C/D     : col = lane&15, row = (lane>>4)*4 + reg (4 f32 / lane)
// R9 (attn2 VALU cut): raw v_exp_f32 via __builtin_amdgcn_exp2f (libm exp2f
// expands to a guarded sequence -> the hidden VALUBusy=55%); row-sum l via
// ones-MFMA (P·1) instead of 32 v_adds + epilogue shuffles; rel_h pre-scaled
// by log2(e) in relk.
// ---------------------------------------------------------------------------

typedef __attribute__((ext_vector_type(8))) short bf16x8;
typedef __attribute__((ext_vector_type(4))) float f32x4;
typedef __attribute__((ext_vector_type(4))) short s16x4;
typedef __attribute__((ext_vector_type(2))) unsigned int u32x2;

__device__ __forceinline__ float b2f(unsigned short h) {
    union { unsigned int u; float f; } v; v.u = ((unsigned int)h) << 16; return v.f;
}
__device__ __forceinline__ unsigned short f2b(float f) {
    union { float f; unsigned int u; } v; v.f = f;
    unsigned int r = v.u + 0x7FFFu + ((v.u >> 16) & 1u);  // RNE
    return (unsigned short)(r >> 16);
}
__device__ __forceinline__ void gl_lds16(const void* g, void* l) {
    __builtin_amdgcn_global_load_lds(
        (const __attribute__((address_space(1))) void*)g,
        (__attribute__((address_space(3))) void*)l, 16, 0, 0);
}

// ---------------------------------------------------------------------------
// fp32 -> bf16 bulk convert into one contiguous region (quad-indexed).
// ---------------------------------------------------------------------------
__global__ __launch_bounds__(256) void cvt_bf16(
        const float* __restrict__ hs, const float* __restrict__ wq,
        const float* __restrict__ wk, const float* __restrict__ wv,
        const float* __restrict__ wo, const float* __restrict__ rph,
        const float* __restrict__ rpw, unsigned short* __restrict__ dst) {
    const int idx = blockIdx.x * 256 + threadIdx.x;
    if (idx >= 1380320) return;
    const float* src;
    int off;
    if      (idx < 786432)  { src = hs;  off = idx; }
    else if (idx < 933888)  { src = wq;  off = idx - 786432; }
    else if (idx < 1081344) { src = wk;  off = idx - 933888; }
    else if (idx < 1228800) { src = wv;  off = idx - 1081344; }
    else if (idx < 1376256) { src = wo;  off = idx - 1228800; }
    else if (idx < 1378288) { src = rph; off = idx - 1376256; }
    else                    { src = rpw; off = idx - 1378288; }
    const float4 v = ((const float4*)src)[off];
    s16x4 o;
    o[0] = (short)f2b(v.x); o[1] = (short)f2b(v.y);
    o[2] = (short)f2b(v.z); o[3] = (short)f2b(v.w);
    *(s16x4*)(dst + (size_t)idx * 4) = o;
}

// ---------------------------------------------------------------------------
// Fused QKV projection, 128x128 tile. z: 0->q, 1->k [n>>6][m][n&63];
// 2->v^T token-PERMUTED (token kk=i*16+quad*4+reg at slot (quad*4+reg)*4+i),
// stored via LDS transpose with coalesced b128 writes.
// ---------------------------------------------------------------------------
__launch_bounds__(256, 3)
__global__ void qkv128(const unsigned short* __restrict__ X,
                       const unsigned short* __restrict__ Wq,
                       const unsigned short* __restrict__ Wk,
                       const unsigned short* __restrict__ Wv,
                       const float* __restrict__ bq,
                       const float* __restrict__ bk,
                       const float* __restrict__ bv,
                       unsigned short* __restrict__ qb,
                       unsigned short* __restrict__ kb,
                       unsigned short* __restrict__ vtb) {
    __shared__ __align__(16) unsigned short sarena[8192];
    unsigned short* abuf = sarena;
    unsigned short* bbuf = sarena + 4096;
    const int tid = threadIdx.x, lane = tid & 63, w = tid >> 6;
    const int r = lane & 15, quad = lane >> 4;
    const int nt = blockIdx.x, mt = blockIdx.y, z = blockIdx.z;
    const unsigned short* W  = (z == 0) ? Wq : (z == 1) ? Wk : Wv;
    const float*          Bv = (z == 0) ? bq : (z == 1) ? bk : bv;
    unsigned short*     outp = (z == 0) ? qb : (z == 1) ? kb : vtb;

    const int c0 = w * 64 + lane, c1 = c0 + 256;
    const unsigned short* xs0 = X + (mt * 128 + (c0 & 127)) * 768 + (c0 >> 7) * 8;
    const unsigned short* xs1 = X + (mt * 128 + (c1 & 127)) * 768 + (c1 >> 7) * 8;
    const unsigned short* ws0 = W + (nt * 128 + (c0 & 127)) * 768 + (c0 >> 7) * 8;
    const unsigned short* ws1 = W + (nt * 128 + (c1 & 127)) * 768 + (c1 >> 7) * 8;

    const int wr = (w & 1) * 64, wc = (w >> 1) * 64;
    f32x4 acc[4][4] = {};
    for (int kt = 0; kt < 24; ++kt) {
        gl_lds16(xs0 + kt * 32, &abuf[w * 512]);
        gl_lds16(xs1 + kt * 32, &abuf[2048 + w * 512]);
        gl_lds16(ws0 + kt * 32, &bbuf[w * 512]);
        gl_lds16(ws1 + kt * 32, &bbuf[2048 + w * 512]);
        __syncthreads();
        bf16x8 af[4], bfr[4];
#pragma unroll
        for (int i = 0; i < 4; ++i)
            af[i] = *(const bf16x8*)&abuf[(quad * 128 + wr + i * 16 + r) * 8];
#pragma unroll
        for (int j = 0; j < 4; ++j)
            bfr[j] = *(const bf16x8*)&bbuf[(quad * 128 + wc + j * 16 + r) * 8];
#pragma unroll
        for (int i = 0; i < 4; ++i)
#pragma unroll
            for (int j = 0; j < 4; ++j)
                acc[i][j] = __builtin_amdgcn_mfma_f32_16x16x32_bf16(af[i], bfr[j], acc[i][j], 0, 0, 0);
        __syncthreads();
    }
    if (z < 2) {
#pragma unroll
        for (int j = 0; j < 4; ++j) {
            const int n = nt * 128 + wc + j * 16 + r;
            const float bias = Bv[n];
            const int nhi = n >> 6, nlo = n & 63;
#pragma unroll
            for (int i = 0; i < 4; ++i) {
#pragma unroll
                for (int reg = 0; reg < 4; ++reg) {
                    const int m = mt * 128 + wr + i * 16 + quad * 4 + reg;
                    outp[(nhi * 4096 + m) * 64 + nlo] = f2b(acc[i][j][reg] + bias);
                }
            }
        }
    } else {
#pragma unroll
        for (int pass = 0; pass < 2; ++pass) {
            if ((w >> 1) == pass) {
#pragma unroll
                for (int j = 0; j < 4; ++j) {
                    const int n_l = j * 16 + r;
                    const float bias = Bv[nt * 128 + pass * 64 + n_l];
                    const int sw = (n_l & 7) << 4;
#pragma unroll
                    for (int reg = 0; reg < 4; ++reg) {
                        const int tokb = (wr + (quad * 4 + reg) * 4) ^ sw;
                        u32x2 d2;
                        d2.x = (unsigned int)f2b(acc[0][j][reg] + bias)
                             | ((unsigned int)f2b(acc[1][j][reg] + bias) << 16);
                        d2.y = (unsigned int)f2b(acc[2][j][reg] + bias)
                             | ((unsigned int)f2b(acc[3][j][reg] + bias) << 16);
                        *(u32x2*)&sarena[n_l * 128 + tokb] = d2;
                    }
                }
            }
            __syncthreads();
#pragma unroll
            for (int c = 0; c < 4; ++c) {
                const int u = c * 256 + tid;
                const int n_l = u >> 4, g = u & 15;
                const int phys = n_l * 128 + ((g * 8) ^ ((n_l & 7) << 4));
                bf16x8 val = *(const bf16x8*)&sarena[phys];
                *(bf16x8*)&outp[(size_t)(nt * 128 + pass * 64 + n_l) * 4096
                                + mt * 128 + g * 8] = val;
            }
            __syncthreads();
        }
    }
}

// ---------------------------------------------------------------------------
// Output projection, 128x128 tile, fp32 row-major out.
// ---------------------------------------------------------------------------
__launch_bounds__(256, 3)
__global__ void out128(const unsigned short* __restrict__ X,
                       const unsigned short* __restrict__ W,
                       const float* __restrict__ Bv,
                       float* __restrict__ out) {
    __shared__ __align__(16) unsigned short abuf[4 * 128 * 8];
    __shared__ __align__(16) unsigned short bbuf[4 * 128 * 8];
    const int tid = threadIdx.x, lane = tid & 63, w = tid >> 6;
    const int r = lane & 15, quad = lane >> 4;
    const int nt = blockIdx.x, mt = blockIdx.y;

    const int c0 = w * 64 + lane, c1 = c0 + 256;
    const unsigned short* xs0 = X + (mt * 128 + (c0 & 127)) * 768 + (c0 >> 7) * 8;
    const unsigned short* xs1 = X + (mt * 128 + (c1 & 127)) * 768 + (c1 >> 7) * 8;
    const unsigned short* ws0 = W + (nt * 128 + (c0 & 127)) * 768 + (c0 >> 7) * 8;
    const unsigned short* ws1 = W + (nt * 128 + (c1 & 127)) * 768 + (c1 >> 7) * 8;

    const int wr = (w & 1) * 64, wc = (w >> 1) * 64;
    f32x4 acc[4][4] = {};
    for (int kt = 0; kt < 24; ++kt) {
        gl_lds16(xs0 + kt * 32, &abuf[w * 512]);
        gl_lds16(xs1 + kt * 32, &abuf[2048 + w * 512]);
        gl_lds16(ws0 + kt * 32, &bbuf[w * 512]);
        gl_lds16(ws1 + kt * 32, &bbuf[2048 + w * 512]);
        __syncthreads();
        bf16x8 af[4], bfr[4];
#pragma unroll
        for (int i = 0; i < 4; ++i)
            af[i] = *(const bf16x8*)&abuf[(quad * 128 + wr + i * 16 + r) * 8];
#pragma unroll
        for (int j = 0; j < 4; ++j)
            bfr[j] = *(const bf16x8*)&bbuf[(quad * 128 + wc + j * 16 + r) * 8];
#pragma unroll
        for (int i = 0; i < 4; ++i)
#pragma unroll
            for (int j = 0; j < 4; ++j)
                acc[i][j] = __builtin_amdgcn_mfma_f32_16x16x32_bf16(af[i], bfr[j], acc[i][j], 0, 0, 0);
        __syncthreads();
    }
#pragma unroll
    for (int j = 0; j < 4; ++j) {
        const int n = nt * 128 + wc + j * 16 + r;
        const float bias = Bv[n];
#pragma unroll
        for (int i = 0; i < 4; ++i) {
#pragma unroll
            for (int reg = 0; reg < 4; ++reg) {
                const int m = mt * 128 + wr + i * 16 + quad * 4 + reg;
                out[m * 768 + n] = acc[i][j][reg] + bias;
            }
        }
    }
}

// ---------------------------------------------------------------------------
// rel_h / rel_w: per (head, a) 64x64x64 GEMM against gathered rel_pos rows.
// mode 0 (rel_h) output is PRE-SCALED by log2(e) (consumed only inside exp2).
// ---------------------------------------------------------------------------
__launch_bounds__(256, 4)
__global__ void relk(const unsigned short* __restrict__ qbuf,
                     const unsigned short* __restrict__ rph,
                     const unsigned short* __restrict__ rpw,
                     unsigned short* __restrict__ rh,
                     unsigned short* __restrict__ rw) {
    __shared__ __align__(16) unsigned short abuf[8 * 64 * 8];
    __shared__ __align__(16) unsigned short bbuf[8 * 64 * 8];
    const int tid = threadIdx.x;
    const int lane = tid & 63, w = tid >> 6;
    const int r = lane & 15, quad = lane >> 4;
    const int a = blockIdx.x, h = blockIdx.y, mode = blockIdx.z;
    const unsigned short* rp = mode ? rpw : rph;
    const float osc = mode ? 1.0f : 1.44269504f;

#pragma unroll
    for (int gg = 0; gg < 2; ++gg) {
        const int g = w * 2 + gg;
        const int arow = mode ? (h * 4096 + lane * 64 + a) : (h * 4096 + a * 64 + lane);
        gl_lds16(qbuf + arow * 64 + g * 8, &abuf[g * 512]);
        const int bidx = a - lane + 63;
        gl_lds16(rp + bidx * 64 + g * 8, &bbuf[g * 512]);
    }
    __syncthreads();

    f32x4 acc[4] = {};
#pragma unroll
    for (int s = 0; s < 2; ++s) {
        bf16x8 af = *(const bf16x8*)&abuf[((s * 4 + quad) * 64 + w * 16 + r) * 8];
#pragma unroll
        for (int j = 0; j < 4; ++j) {
            bf16x8 bfr = *(const bf16x8*)&bbuf[((s * 4 + quad) * 64 + j * 16 + r) * 8];
            acc[j] = __builtin_amdgcn_mfma_f32_16x16x32_bf16(af, bfr, acc[j], 0, 0, 0);
        }
    }
    unsigned short* out = mode ? rw : rh;
#pragma unroll
    for (int j = 0; j < 4; ++j) {
#pragma unroll
        for (int reg = 0; reg < 4; ++reg) {
            const int m = w * 16 + quad * 4 + reg, n = j * 16 + r;
            const int t = mode ? (h * 4096 + m * 64 + a) : (h * 4096 + a * 64 + m);
            out[t * 64 + n] = f2b(acc[j][reg] * osc);
        }
    }
}

// ---------------------------------------------------------------------------
// Flash attention, split-K: block = 128-query tile (2 qgroups of 16 / wave),
// split sp covers key tiles sp*32..sp*32+31. kf/vf LDS reads shared across
// both qgroups. Fixed softmax ref (m=0) -> partials are plain sums.
// l computed via ones-MFMA row-sum of the packed bf16 P (consistent with O).
// ---------------------------------------------------------------------------
__launch_bounds__(256, 3)
__global__ void attn2(const unsigned short* __restrict__ qbuf,
                      const unsigned short* __restrict__ kbuf,
                      const unsigned short* __restrict__ vtbuf,
                      const unsigned short* __restrict__ rhb,
                      const unsigned short* __restrict__ rwb,
                      float* __restrict__ po, float* __restrict__ lp) {
    __shared__ __align__(16) unsigned short skb[4096];   // K [d_oct][key][8]
    __shared__ __align__(16) unsigned short svb[4096];   // V^T [scol_oct][d][8]
    __shared__ __align__(16) unsigned short spb[9216];   // P x2 groups, stride 72
    __shared__ __align__(16) unsigned short srh[8192];   // rel_h*L2E [ki_oct][ql][8]
    const int tid = threadIdx.x;
    const int lane = tid & 63, w = tid >> 6;
    const int r = lane & 15, quad = lane >> 4;
    const int qt = blockIdx.x, h = blockIdx.y, sp = blockIdx.z;
    const float L2E = 1.44269504f;
    const float SC = 0.125f * L2E;

#pragma unroll
    for (int i = 0; i < 4; ++i) {
        const int gp = i * 2 + (w >> 1), ql = (w & 1) * 64 + lane;
        gl_lds16(rhb + (h * 4096 + qt * 128 + ql) * 64 + gp * 8,
                 &srh[(i * 256 + w * 64) * 8]);
    }
    bf16x8 qf[2][2];
#pragma unroll
    for (int g = 0; g < 2; ++g) {
        const unsigned short* qrow =
            qbuf + (h * 4096 + qt * 128 + g * 64 + w * 16 + r) * 64;
        qf[g][0] = *(const bf16x8*)(qrow + quad * 8);
        qf[g][1] = *(const bf16x8*)(qrow + 32 + quad * 8);
    }
    float rwL[2][4][4];
#pragma unroll
    for (int g = 0; g < 2; ++g) {
        const unsigned short* rwrow = rwb + (h * 4096 + qt * 128 + g * 64) * 64;
#pragma unroll
        for (int reg = 0; reg < 4; ++reg) {
            const int ql = w * 16 + quad * 4 + reg;
#pragma unroll
            for (int j = 0; j < 4; ++j)
                rwL[g][j][reg] = b2f(rwrow[ql * 64 + j * 16 + r]) * L2E;
        }
    }
    bf16x8 onesf;
#pragma unroll
    for (int i = 0; i < 8; ++i) onesf[i] = (short)0x3F80;  // bf16 1.0

    f32x4 lacc[2] = {};
    f32x4 oacc[2][4] = {};
    __syncthreads();

    for (int tl = 0; tl < 32; ++tl) {
        const int t = sp * 32 + tl;
#pragma unroll
        for (int gg = 0; gg < 2; ++gg) {
            const int g = w * 2 + gg;
            gl_lds16(kbuf + (h * 4096 + t * 64 + lane) * 64 + g * 8, &skb[g * 512]);
            gl_lds16(vtbuf + (h * 64 + lane) * 4096 + t * 64 + g * 8, &svb[g * 512]);
        }
        __syncthreads();

        // S for both qgroups; kf read once, used twice
        f32x4 s0[4] = {}, s1[4] = {};
#pragma unroll
        for (int s2 = 0; s2 < 2; ++s2) {
#pragma unroll
            for (int j = 0; j < 4; ++j) {
                bf16x8 kf = *(const bf16x8*)&skb[((s2 * 4 + quad) * 64 + j * 16 + r) * 8];
                s0[j] = __builtin_amdgcn_mfma_f32_16x16x32_bf16(qf[0][s2], kf, s0[j], 0, 0, 0);
                s1[j] = __builtin_amdgcn_mfma_f32_16x16x32_bf16(qf[1][s2], kf, s1[j], 0, 0, 0);
            }
        }
        // softmax + pack per qgroup (raw v_exp_f32; args bounded)
#pragma unroll
        for (int g = 0; g < 2; ++g) {
            float rh2[4];
#pragma unroll
            for (int reg = 0; reg < 4; ++reg)
                rh2[reg] = b2f(srh[((t >> 3) * 128 + g * 64 + w * 16 + quad * 4 + reg) * 8
                                   + (t & 7)]);  // pre-scaled by log2e in relk
#pragma unroll
            for (int reg = 0; reg < 4; ++reg) {
                unsigned int u[4];
#pragma unroll
                for (int j = 0; j < 4; ++j) {
                    const float sv = g ? s1[j][reg] : s0[j][reg];
                    const float p = __builtin_amdgcn_exp2f(
                        fmaf(sv, SC, rh2[reg] + rwL[g][j][reg]));
                    union { float f; unsigned int q; } cv; cv.f = p;
                    u[j] = cv.q;
                }
                u32x2 d;
                d.x = __builtin_amdgcn_perm(u[1], u[0], 0x07060302);
                d.y = __builtin_amdgcn_perm(u[3], u[2], 0x07060302);
                *(u32x2*)&spb[g * 4608 + w * 1152 + (quad * 4 + reg) * 72 + r * 4] = d;
            }
        }
        // PV: vf read once, used twice; l row-sum via ones-MFMA
#pragma unroll
        for (int s = 0; s < 2; ++s) {
            bf16x8 pf0 = *(const bf16x8*)&spb[w * 1152 + r * 72 + s * 32 + quad * 8];
            bf16x8 pf1 = *(const bf16x8*)&spb[4608 + w * 1152 + r * 72 + s * 32 + quad * 8];
            lacc[0] = __builtin_amdgcn_mfma_f32_16x16x32_bf16(pf0, onesf, lacc[0], 0, 0, 0);
            lacc[1] = __builtin_amdgcn_mfma_f32_16x16x32_bf16(pf1, onesf, lacc[1], 0, 0, 0);
#pragma unroll
            for (int j = 0; j < 4; ++j) {
                bf16x8 vf = *(const bf16x8*)&svb[((s * 4 + quad) * 64 + j * 16 + r) * 8];
                oacc[0][j] = __builtin_amdgcn_mfma_f32_16x16x32_bf16(pf0, vf, oacc[0][j], 0, 0, 0);
                oacc[1][j] = __builtin_amdgcn_mfma_f32_16x16x32_bf16(pf1, vf, oacc[1][j], 0, 0, 0);
            }
        }
        __syncthreads();
    }
    // epilogue: store partials (lacc already holds full per-query row sums)
    const size_t pbase = ((size_t)(sp * 12 + h) * 4096 + qt * 128);
#pragma unroll
    for (int g = 0; g < 2; ++g) {
        const int qrow = g * 64 + w * 16 + quad * 4;
#pragma unroll
        for (int reg = 0; reg < 4; ++reg) {
#pragma unroll
            for (int j = 0; j < 4; ++j)
                po[(pbase + qrow + reg) * 64 + j * 16 + r] = oacc[g][j][reg];
            if (r == 0) lp[pbase + qrow + reg] = lacc[g][reg];
        }
    }
}

// ---------------------------------------------------------------------------
// Combine split-K partials: ab[t][h*64+d] = (po0+po1)/(l0+l1) as bf16.
// ---------------------------------------------------------------------------
__global__ __launch_bounds__(256) void combine(const float* __restrict__ po,
                                               const float* __restrict__ lp,
                                               unsigned short* __restrict__ ab) {
    const unsigned int idx = blockIdx.x * 256 + threadIdx.x;  // 0..393215
    const unsigned int tok = idx / 96u;
    const unsigned int part = idx - tok * 96u;
    const int c = part * 8, h = c >> 6, d = c & 63;
    const float* p0 = po + ((size_t)h * 4096 + tok) * 64 + d;
    const float* p1 = po + ((size_t)(12 + h) * 4096 + tok) * 64 + d;
    const float inv = 1.f / (lp[h * 4096 + tok] + lp[(12 + h) * 4096 + tok]);
    const float4 a0 = *(const float4*)p0, b0 = *(const float4*)(p0 + 4);
    const float4 a1 = *(const float4*)p1, b1 = *(const float4*)(p1 + 4);
    s16x4 o0, o1;
    o0[0] = (short)f2b((a0.x + a1.x) * inv); o0[1] = (short)f2b((a0.y + a1.y) * inv);
    o0[2] = (short)f2b((a0.z + a1.z) * inv); o0[3] = (short)f2b((a0.w + a1.w) * inv);
    o1[0] = (short)f2b((b0.x + b1.x) * inv); o1[1] = (short)f2b((b0.y + b1.y) * inv);
    o1[2] = (short)f2b((b0.z + b1.z) * inv); o1[3] = (short)f2b((b0.w + b1.w) * inv);
    unsigned short* dst = ab + (size_t)tok * 768 + c;
    *(s16x4*)dst = o0;
    *(s16x4*)(dst + 4) = o1;
}

// ---------------------------------------------------------------------------
extern "C" void kernel_launch(void* const* d_in, const int* in_sizes, int n_in,
                              void* d_out, int out_size, void* d_ws, size_t ws_size,
                              hipStream_t stream) {
    const float* hs  = (const float*)d_in[0];
    const float* wq  = (const float*)d_in[1];
    const float* bq  = (const float*)d_in[2];
    const float* wk  = (const float*)d_in[3];
    const float* bk  = (const float*)d_in[4];
    const float* wv  = (const float*)d_in[5];
    const float* bv  = (const float*)d_in[6];
    const float* wo  = (const float*)d_in[7];
    const float* bo  = (const float*)d_in[8];
    const float* rph = (const float*)d_in[9];
    const float* rpw = (const float*)d_in[10];

    unsigned short* ws = (unsigned short*)d_ws;
    const int HS = 3145728, WN = 589824, RP = 8128;
    const int HB = 12 * 4096 * 64;
    unsigned short* hsb  = ws;
    unsigned short* wqb  = hsb  + HS;
    unsigned short* wkb  = wqb  + WN;
    unsigned short* wvb  = wkb  + WN;
    unsigned short* wob  = wvb  + WN;
    unsigned short* rphb = wob  + WN;
    unsigned short* rpwb = rphb + RP;
    unsigned short* qb   = rpwb + RP;          // q   [h][t][d]
    unsigned short* kb   = qb   + HB;          // k   [h][t][d]
    unsigned short* vtb  = kb   + HB;          // v^T [h][d][t], token-permuted
    unsigned short* rhb  = vtb  + HB;          // rel_h*log2e [h][t][ki]
    unsigned short* rwb  = rhb  + HB;          // rel_w [h][t][kj]
    unsigned short* ab   = rwb  + HB;          // attn out [t][768]
    float* po = (float*)(ab + HB);             // O_num partials [2][12][4096][64]
    float* lp = po + 2 * 12 * 4096 * 64;       // l partials [2][12][4096]

    cvt_bf16<<<dim3((1380320 + 255) / 256), 256, 0, stream>>>(
        hs, wq, wk, wv, wo, rph, rpw, hsb);
    qkv128<<<dim3(6, 32, 3), 256, 0, stream>>>(
        hsb, wqb, wkb, wvb, bq, bk, bv, qb, kb, vtb);
    relk<<<dim3(64, 12, 2), 256, 0, stream>>>(qb, rphb, rpwb, rhb, rwb);
    attn2<<<dim3(32, 12, 2), 256, 0, stream>>>(qb, kb, vtb, rhb, rwb, po, lp);
    combine<<<dim3(1536), 256, 0, stream>>>(po, lp, ab);
    out128<<<dim3(6, 32), 256, 0, stream>>>(ab, wob, bo, (float*)d_out);
}